// Round 7
// baseline (2282.118 us; speedup 1.0000x reference)
//
#include <hip/hip_runtime.h>
#include <hip/hip_bf16.h>

typedef __hip_bfloat16 bf16;
typedef unsigned short u16;
typedef __attribute__((ext_vector_type(8))) short s16x8;   // 8 bf16 (4 VGPRs)
typedef __attribute__((ext_vector_type(4))) short s16x4;   // 4 bf16 (2 VGPRs)
typedef __attribute__((ext_vector_type(4))) float f32x4;   // MFMA accumulator

// ---------------- dtype-agnostic input loads ----------------
__device__ __forceinline__ float bfb(unsigned short b) {
    union { unsigned u; float f; } v; v.u = ((unsigned)b) << 16; return v.f;
}
__device__ __forceinline__ float ldin(const void* p, size_t i, bool f32) {
    return f32 ? ((const float*)p)[i] : bfb(((const unsigned short*)p)[i]);
}
__device__ __forceinline__ void ld4(const void* p, size_t i, bool f32,
                                    float& x, float& y, float& z, float& w) {
    if (f32) {
        float4 v = *reinterpret_cast<const float4*>((const float*)p + i);
        x = v.x; y = v.y; z = v.z; w = v.w;
    } else {
        ushort4 u = *reinterpret_cast<const ushort4*>((const unsigned short*)p + i);
        x = bfb(u.x); y = bfb(u.y); z = bfb(u.z); w = bfb(u.w);
    }
}
__device__ __forceinline__ u16 f2b(float x) {
    bf16 h = __float2bfloat16(x);
    return *reinterpret_cast<u16*>(&h);
}
// bf16x2 split: x = hi + lo, hi = truncate-to-bf16 (exact), lo = RN-bf16(x - hi)
__device__ __forceinline__ void split2(float x, u16& h, u16& l) {
    unsigned u = __float_as_uint(x);
    h = (u16)(u >> 16);
    float rem = x - __uint_as_float(u & 0xFFFF0000u);
    l = f2b(rem);
}
// XCD-aware block swizzle (T1)
__device__ __forceinline__ int xcd_swz(int F, int nwg) {
    return ((nwg & 7) == 0) ? ((F & 7) * (nwg >> 3) + (F >> 3)) : F;
}
// 72B-stride LDS fragment access: 8B-aligned -> paired b64, conflict-free
union F8 { s16x8 v; s16x4 h[2]; };
__device__ __forceinline__ s16x8 ldfrag(const u16* p) {
    F8 f;
    f.h[0] = *reinterpret_cast<const s16x4*>(p);
    f.h[1] = *reinterpret_cast<const s16x4*>(p + 4);
    return f.v;
}
__device__ __forceinline__ void stfrag(u16* p, s16x8 v) {
    F8 f; f.v = v;
    *reinterpret_cast<s16x4*>(p)     = f.h[0];
    *reinterpret_cast<s16x4*>(p + 4) = f.h[1];
}
// LDS-only barrier: lgkm drain + raw s_barrier. No vmcnt(0) drain, so
// prefetched global loads stay in flight across the barrier.
__device__ __forceinline__ void barsync() {
    asm volatile("s_waitcnt lgkmcnt(0)" ::: "memory");
    __builtin_amdgcn_s_barrier();
}

// ---------------- problem constants ----------------
constexpr int C_B = 16, C_S = 511, C_L = 512, C_NHID = 512;
constexpr int C_N = C_B * C_S;       // 8176
constexpr int C_MTOK = C_B * C_L;    // 8192
constexpr int C_E = 131072;
constexpr int C_QKVD = 1536;

// ---------------- workspace layout (f32 element offsets) ----------------
enum : size_t {
    OFF_H     = 0,
    OFF_QKV   = 4194304,
    OFF_O     = 16777216,
    OFF_X     = 20971520,
    OFF_MID   = 25165824,
    OFF_PRE   = 41943040,
    OFF_T8    = OFF_PRE,
    OFF_GCAT0 = OFF_PRE + 262144,
    OFF_GCAT1 = OFF_GCAT0 + 131072,
    OFF_DCAT0 = OFF_GCAT1 + 131072,
    OFF_DCAT1 = OFF_DCAT0 + 256,
    OFF_DEG   = OFF_DCAT1 + 256,
    OFF_FLAG  = OFF_DEG + 32768
};

// ---------------- dtype detection ----------------
__global__ void detect_kernel(const unsigned* __restrict__ g, int* __restrict__ flag) {
    *flag = (g[0] == 0x3F800000u) ? 1 : 0;
}

// ---------------- embedding ----------------
__global__ __launch_bounds__(256) void embed_kernel(
    const void* __restrict__ emb, const void* __restrict__ pos,
    const int* __restrict__ idxs, const int* __restrict__ flag,
    float* __restrict__ h)
{
    const bool f = (*flag) != 0;
    int token = blockIdx.x;
    int tid = threadIdx.x;
    int b = token >> 9, t = token & 511;
    int id = (t == 0) ? 0 : idxs[b * C_S + t - 1];
    size_t eo = (size_t)id * C_NHID, po = (size_t)t * C_NHID, ho = (size_t)token * C_NHID;
    h[ho + tid]       = ldin(emb, eo + tid, f)       + ldin(pos, po + tid, f);
    h[ho + tid + 256] = ldin(emb, eo + tid + 256, f) + ldin(pos, po + tid + 256, f);
}

// ---------------- weight transpose + bf16x2 split (dtype via flag) ----------
__global__ __launch_bounds__(256) void wtrans2_kernel(
    const void* __restrict__ Wsrc, size_t srcOff, const int* __restrict__ flag,
    u16* __restrict__ Bh, u16* __restrict__ Bl, int K, int N)
{
    const bool f = (*flag) != 0;
    __shared__ float s[32][33];
    int nb = blockIdx.x << 5, kb = blockIdx.y << 5;
    int c = threadIdx.x & 31, r0 = (threadIdx.x >> 5) << 2;
#pragma unroll
    for (int i = 0; i < 4; ++i)
        s[r0 + i][c] = ldin(Wsrc, srcOff + (size_t)(kb + r0 + i) * N + nb + c, f);
    __syncthreads();
#pragma unroll
    for (int i = 0; i < 4; ++i) {
        u16 h, l;
        split2(s[c][r0 + i], h, l);
        size_t o = (size_t)(nb + r0 + i) * K + kb + c;
        Bh[o] = h; Bl[o] = l;
    }
}

// ---------------- MFMA bf16x2-SPLIT GEMM, 128x64 tile -----------------------
// Register-prefetch + LDS double-buffer (1 barrier/K-step). 36-u16 row pad
// (72B stride, 18 banks, gcd(18,32)=2 -> 16 distinct start banks) with b64
// fragment moves: conflict-free LDS.
__global__ __launch_bounds__(256, 2) void msgemm_kernel(
    const float* __restrict__ A,
    const u16* __restrict__ Bh, const u16* __restrict__ Bl,
    const void* __restrict__ biasB, size_t bOff,
    const float* __restrict__ biasF,
    const float* __restrict__ res, float resScale,
    const float* __restrict__ rowDeg, int relu,
    const int* __restrict__ flag,
    float* __restrict__ C, int M, int K, int Nc, int ldc)
{
    const bool f32in = (*flag) != 0;
    __shared__ __align__(16) u16 sAh[2][128][36];
    __shared__ __align__(16) u16 sAl[2][128][36];
    __shared__ __align__(16) u16 sBh[2][64][36];
    __shared__ __align__(16) u16 sBl[2][64][36];
    const int tid = threadIdx.x;
    const int nwg = gridDim.x * gridDim.y;
    const int swz = xcd_swz(blockIdx.y * gridDim.x + blockIdx.x, nwg);
    const int bm = (swz / gridDim.x) << 7, bn = (swz % gridDim.x) << 6;
    const int lane = tid & 63, lr = lane & 15, lg = lane >> 4;
    const int wave = tid >> 6, wm = wave >> 1, wn = wave & 1;

    f32x4 acc[4][2];
#pragma unroll
    for (int m = 0; m < 4; ++m)
#pragma unroll
        for (int n = 0; n < 2; ++n) {
            f32x4 z = {0.f, 0.f, 0.f, 0.f};
            acc[m][n] = z;
        }

    const int sr = tid >> 1, sk = (tid & 1) << 4;
    const int am = bm + sr;
    const bool aok = am < M;
    const float* ap = A + (size_t)am * K + sk;
    const int brn = tid >> 2, bk = (tid & 3) << 3;
    const u16* bph = Bh + (size_t)(bn + brn) * K + bk;
    const u16* bpl = Bl + (size_t)(bn + brn) * K + bk;

    float4 a0, a1, a2, a3;
    s16x8 pbh, pbl;

    auto ld_tile = [&](int kk) {
        if (aok) {
            a0 = *reinterpret_cast<const float4*>(ap + kk);
            a1 = *reinterpret_cast<const float4*>(ap + kk + 4);
            a2 = *reinterpret_cast<const float4*>(ap + kk + 8);
            a3 = *reinterpret_cast<const float4*>(ap + kk + 12);
        }
        pbh = *reinterpret_cast<const s16x8*>(bph + kk);
        pbl = *reinterpret_cast<const s16x8*>(bpl + kk);
    };
    auto st_tile = [&](int buf) {
        u16 tah[16], tal[16];
        if (aok) {
            split2(a0.x, tah[0], tal[0]);  split2(a0.y, tah[1], tal[1]);
            split2(a0.z, tah[2], tal[2]);  split2(a0.w, tah[3], tal[3]);
            split2(a1.x, tah[4], tal[4]);  split2(a1.y, tah[5], tal[5]);
            split2(a1.z, tah[6], tal[6]);  split2(a1.w, tah[7], tal[7]);
            split2(a2.x, tah[8], tal[8]);  split2(a2.y, tah[9], tal[9]);
            split2(a2.z, tah[10], tal[10]); split2(a2.w, tah[11], tal[11]);
            split2(a3.x, tah[12], tal[12]); split2(a3.y, tah[13], tal[13]);
            split2(a3.z, tah[14], tal[14]); split2(a3.w, tah[15], tal[15]);
        } else {
#pragma unroll
            for (int i = 0; i < 16; ++i) { tah[i] = 0; tal[i] = 0; }
        }
        stfrag(&sAh[buf][sr][sk],     *reinterpret_cast<s16x8*>(&tah[0]));
        stfrag(&sAh[buf][sr][sk + 8], *reinterpret_cast<s16x8*>(&tah[8]));
        stfrag(&sAl[buf][sr][sk],     *reinterpret_cast<s16x8*>(&tal[0]));
        stfrag(&sAl[buf][sr][sk + 8], *reinterpret_cast<s16x8*>(&tal[8]));
        stfrag(&sBh[buf][brn][bk], pbh);
        stfrag(&sBl[buf][brn][bk], pbl);
    };

    // prologue: stage tile0, prefetch tile1
    ld_tile(0);
    st_tile(0);
    ld_tile((32 < K) ? 32 : 0);
    barsync();

    int cur = 0;
    for (int k0 = 0; k0 < K; k0 += 32) {
        if (k0 + 32 < K) {
            st_tile(cur ^ 1);                       // write next buffer
            ld_tile((k0 + 64 < K) ? k0 + 64 : 0);   // prefetch tile k0+64
        }
        s16x8 fah[4], fal[4], fbh[2], fbl[2];
#pragma unroll
        for (int m = 0; m < 4; ++m) {
            fah[m] = ldfrag(&sAh[cur][wm * 64 + m * 16 + lr][lg * 8]);
            fal[m] = ldfrag(&sAl[cur][wm * 64 + m * 16 + lr][lg * 8]);
        }
#pragma unroll
        for (int n = 0; n < 2; ++n) {
            fbh[n] = ldfrag(&sBh[cur][wn * 32 + n * 16 + lr][lg * 8]);
            fbl[n] = ldfrag(&sBl[cur][wn * 32 + n * 16 + lr][lg * 8]);
        }
#pragma unroll
        for (int m = 0; m < 4; ++m)
#pragma unroll
            for (int n = 0; n < 2; ++n) {
                acc[m][n] = __builtin_amdgcn_mfma_f32_16x16x32_bf16(fah[m], fbh[n], acc[m][n], 0, 0, 0);
                acc[m][n] = __builtin_amdgcn_mfma_f32_16x16x32_bf16(fah[m], fbl[n], acc[m][n], 0, 0, 0);
                acc[m][n] = __builtin_amdgcn_mfma_f32_16x16x32_bf16(fal[m], fbh[n], acc[m][n], 0, 0, 0);
            }
        barsync();
        cur ^= 1;
    }

#pragma unroll
    for (int m = 0; m < 4; ++m) {
#pragma unroll
        for (int r = 0; r < 4; ++r) {
            int row = bm + wm * 64 + m * 16 + lg * 4 + r;
            if (row >= M) continue;
            float rs = rowDeg ? rsqrtf(fmaxf(rowDeg[row], 1.f)) : 1.f;
#pragma unroll
            for (int n = 0; n < 2; ++n) {
                int col = bn + wn * 32 + n * 16 + lr;
                float v = acc[m][n][r];
                if (biasB) v += ldin(biasB, bOff + col, f32in);
                if (biasF) v += biasF[col];
                v *= rs;
                if (res) v += resScale * res[(size_t)row * Nc + col];
                if (relu) v = fmaxf(v, 0.f);
                C[(size_t)row * ldc + col] = v;
            }
        }
    }
}

// ---------------- MFMA bf16x2-SPLIT GEMM, 128x128 tile (big-N GEMMs) ---------
__global__ __launch_bounds__(256, 2) void msgemm2_kernel(
    const float* __restrict__ A,
    const u16* __restrict__ Bh, const u16* __restrict__ Bl,
    const void* __restrict__ biasB, size_t bOff,
    const int relu, const int* __restrict__ flag,
    float* __restrict__ C, int M, int K, int Nc, int ldc)
{
    const bool f32in = (*flag) != 0;
    __shared__ __align__(16) u16 sAh[2][128][36];
    __shared__ __align__(16) u16 sAl[2][128][36];
    __shared__ __align__(16) u16 sBh[2][128][36];
    __shared__ __align__(16) u16 sBl[2][128][36];
    const int tid = threadIdx.x;
    const int nwg = gridDim.x * gridDim.y;
    const int swz = xcd_swz(blockIdx.y * gridDim.x + blockIdx.x, nwg);
    const int bm = (swz / gridDim.x) << 7, bn = (swz % gridDim.x) << 7;
    const int lane = tid & 63, lr = lane & 15, lg = lane >> 4;
    const int wave = tid >> 6, wm = wave >> 1, wn = wave & 1;

    f32x4 acc[4][4];
#pragma unroll
    for (int m = 0; m < 4; ++m)
#pragma unroll
        for (int n = 0; n < 4; ++n) {
            f32x4 z = {0.f, 0.f, 0.f, 0.f};
            acc[m][n] = z;
        }

    const int sr = tid >> 1, sk = (tid & 1) << 4;
    const int am = bm + sr;
    const bool aok = am < M;
    const float* ap = A + (size_t)am * K + sk;
    const u16* bph = Bh + (size_t)(bn + sr) * K + sk;
    const u16* bpl = Bl + (size_t)(bn + sr) * K + sk;

    float4 a0, a1, a2, a3;
    s16x8 pbh0, pbh1, pbl0, pbl1;

    auto ld_tile = [&](int kk) {
        if (aok) {
            a0 = *reinterpret_cast<const float4*>(ap + kk);
            a1 = *reinterpret_cast<const float4*>(ap + kk + 4);
            a2 = *reinterpret_cast<const float4*>(ap + kk + 8);
            a3 = *reinterpret_cast<const float4*>(ap + kk + 12);
        }
        pbh0 = *reinterpret_cast<const s16x8*>(bph + kk);
        pbh1 = *reinterpret_cast<const s16x8*>(bph + kk + 8);
        pbl0 = *reinterpret_cast<const s16x8*>(bpl + kk);
        pbl1 = *reinterpret_cast<const s16x8*>(bpl + kk + 8);
    };
    auto st_tile = [&](int buf) {
        u16 tah[16], tal[16];
        if (aok) {
            split2(a0.x, tah[0], tal[0]);  split2(a0.y, tah[1], tal[1]);
            split2(a0.z, tah[2], tal[2]);  split2(a0.w, tah[3], tal[3]);
            split2(a1.x, tah[4], tal[4]);  split2(a1.y, tah[5], tal[5]);
            split2(a1.z, tah[6], tal[6]);  split2(a1.w, tah[7], tal[7]);
            split2(a2.x, tah[8], tal[8]);  split2(a2.y, tah[9], tal[9]);
            split2(a2.z, tah[10], tal[10]); split2(a2.w, tah[11], tal[11]);
            split2(a3.x, tah[12], tal[12]); split2(a3.y, tah[13], tal[13]);
            split2(a3.z, tah[14], tal[14]); split2(a3.w, tah[15], tal[15]);
        } else {
#pragma unroll
            for (int i = 0; i < 16; ++i) { tah[i] = 0; tal[i] = 0; }
        }
        stfrag(&sAh[buf][sr][sk],     *reinterpret_cast<s16x8*>(&tah[0]));
        stfrag(&sAh[buf][sr][sk + 8], *reinterpret_cast<s16x8*>(&tah[8]));
        stfrag(&sAl[buf][sr][sk],     *reinterpret_cast<s16x8*>(&tal[0]));
        stfrag(&sAl[buf][sr][sk + 8], *reinterpret_cast<s16x8*>(&tal[8]));
        stfrag(&sBh[buf][sr][sk],     pbh0);
        stfrag(&sBh[buf][sr][sk + 8], pbh1);
        stfrag(&sBl[buf][sr][sk],     pbl0);
        stfrag(&sBl[buf][sr][sk + 8], pbl1);
    };

    ld_tile(0);
    st_tile(0);
    ld_tile((32 < K) ? 32 : 0);
    barsync();

    int cur = 0;
    for (int k0 = 0; k0 < K; k0 += 32) {
        if (k0 + 32 < K) {
            st_tile(cur ^ 1);
            ld_tile((k0 + 64 < K) ? k0 + 64 : 0);
        }
        s16x8 fah[4], fal[4], fbh[4], fbl[4];
#pragma unroll
        for (int m = 0; m < 4; ++m) {
            fah[m] = ldfrag(&sAh[cur][wm * 64 + m * 16 + lr][lg * 8]);
            fal[m] = ldfrag(&sAl[cur][wm * 64 + m * 16 + lr][lg * 8]);
        }
#pragma unroll
        for (int n = 0; n < 4; ++n) {
            fbh[n] = ldfrag(&sBh[cur][wn * 64 + n * 16 + lr][lg * 8]);
            fbl[n] = ldfrag(&sBl[cur][wn * 64 + n * 16 + lr][lg * 8]);
        }
#pragma unroll
        for (int m = 0; m < 4; ++m)
#pragma unroll
            for (int n = 0; n < 4; ++n) {
                acc[m][n] = __builtin_amdgcn_mfma_f32_16x16x32_bf16(fah[m], fbh[n], acc[m][n], 0, 0, 0);
                acc[m][n] = __builtin_amdgcn_mfma_f32_16x16x32_bf16(fah[m], fbl[n], acc[m][n], 0, 0, 0);
                acc[m][n] = __builtin_amdgcn_mfma_f32_16x16x32_bf16(fal[m], fbh[n], acc[m][n], 0, 0, 0);
            }
        barsync();
        cur ^= 1;
    }

#pragma unroll
    for (int m = 0; m < 4; ++m) {
#pragma unroll
        for (int r = 0; r < 4; ++r) {
            int row = bm + wm * 64 + m * 16 + lg * 4 + r;
            if (row >= M) continue;
#pragma unroll
            for (int n = 0; n < 4; ++n) {
                int col = bn + wn * 64 + n * 16 + lr;
                float v = acc[m][n][r];
                if (biasB) v += ldin(biasB, bOff + col, f32in);
                if (relu) v = fmaxf(v, 0.f);
                C[(size_t)row * ldc + col] = v;
            }
        }
    }
}

// ---------------- MFMA bf16x2-split flash attention ------------------------
__global__ __launch_bounds__(256) void mattn_kernel(
    const float* __restrict__ qkv, float* __restrict__ o_out)
{
    __shared__ __align__(16) u16 sKh[64][72], sKl[64][72];   // [kp][d]
    __shared__ __align__(16) u16 sVh[64][72], sVl[64][72];   // [dv][kp] (V^T)
    __shared__ __align__(16) u16 sPh[4][16][72], sPl[4][16][72];
    const int blk = xcd_swz(blockIdx.x, gridDim.x);   // same-(b,h) blocks -> same XCD
    const int b = blk >> 6, h = (blk >> 3) & 7, qt = blk & 7;
    const int tid = threadIdx.x;
    const int lane = tid & 63, lr = lane & 15, lg = lane >> 4;
    const int w = tid >> 6;

    s16x8 qh[2], ql[2];
    {
        const float* qp = qkv + (size_t)(b * C_L + qt * 64 + w * 16 + lr) * C_QKVD + h * 192;
#pragma unroll
        for (int c = 0; c < 2; ++c) {
            int d0 = c * 32 + lg * 8;
            u16 th[8], tl[8];
#pragma unroll
            for (int i = 0; i < 8; i += 4) {
                float4 v = *reinterpret_cast<const float4*>(qp + d0 + i);
                split2(v.x * 0.125f, th[i],     tl[i]);
                split2(v.y * 0.125f, th[i + 1], tl[i + 1]);
                split2(v.z * 0.125f, th[i + 2], tl[i + 2]);
                split2(v.w * 0.125f, th[i + 3], tl[i + 3]);
            }
            qh[c] = *reinterpret_cast<s16x8*>(th);
            ql[c] = *reinterpret_cast<s16x8*>(tl);
        }
    }

    f32x4 accO[4];
#pragma unroll
    for (int n = 0; n < 4; ++n) { f32x4 z = {0.f, 0.f, 0.f, 0.f}; accO[n] = z; }
    float m[4] = {-3.0e38f, -3.0e38f, -3.0e38f, -3.0e38f};
    float l[4] = {0.f, 0.f, 0.f, 0.f};

    const float* kvb = qkv + (size_t)b * C_L * C_QKVD + h * 192;
    const int kp = tid >> 2;
    const int d0 = (tid & 3) << 4;

    for (int jt = 0; jt < 8; ++jt) {
        __syncthreads();
        {
            const float* kr = kvb + (size_t)(jt * 64 + kp) * C_QKVD + 64 + d0;
            const float* vr = kr + 64;
#pragma unroll
            for (int i = 0; i < 16; i += 4) {
                float4 kv = *reinterpret_cast<const float4*>(kr + i);
                float4 vv = *reinterpret_cast<const float4*>(vr + i);
                u16 th[4], tl[4];
                split2(kv.x, th[0], tl[0]); split2(kv.y, th[1], tl[1]);
                split2(kv.z, th[2], tl[2]); split2(kv.w, th[3], tl[3]);
                *reinterpret_cast<ushort4*>(&sKh[kp][d0 + i]) = *reinterpret_cast<ushort4*>(th);
                *reinterpret_cast<ushort4*>(&sKl[kp][d0 + i]) = *reinterpret_cast<ushort4*>(tl);
                u16 hh, ll;
                split2(vv.x, hh, ll); sVh[d0 + i][kp]     = hh; sVl[d0 + i][kp]     = ll;
                split2(vv.y, hh, ll); sVh[d0 + i + 1][kp] = hh; sVl[d0 + i + 1][kp] = ll;
                split2(vv.z, hh, ll); sVh[d0 + i + 2][kp] = hh; sVl[d0 + i + 2][kp] = ll;
                split2(vv.w, hh, ll); sVh[d0 + i + 3][kp] = hh; sVl[d0 + i + 3][kp] = ll;
            }
        }
        __syncthreads();

        f32x4 accS[4];
#pragma unroll
        for (int n = 0; n < 4; ++n) { f32x4 z = {0.f, 0.f, 0.f, 0.f}; accS[n] = z; }
#pragma unroll
        for (int n = 0; n < 4; ++n)
#pragma unroll
            for (int c = 0; c < 2; ++c) {
                s16x8 kh = *reinterpret_cast<const s16x8*>(&sKh[n * 16 + lr][c * 32 + lg * 8]);
                s16x8 kl = *reinterpret_cast<const s16x8*>(&sKl[n * 16 + lr][c * 32 + lg * 8]);
                accS[n] = __builtin_amdgcn_mfma_f32_16x16x32_bf16(qh[c], kh, accS[n], 0, 0, 0);
                accS[n] = __builtin_amdgcn_mfma_f32_16x16x32_bf16(qh[c], kl, accS[n], 0, 0, 0);
                accS[n] = __builtin_amdgcn_mfma_f32_16x16x32_bf16(ql[c], kh, accS[n], 0, 0, 0);
            }

#pragma unroll
        for (int r = 0; r < 4; ++r) {
            float mt = fmaxf(fmaxf(accS[0][r], accS[1][r]), fmaxf(accS[2][r], accS[3][r]));
            mt = fmaxf(mt, __shfl_xor(mt, 1));
            mt = fmaxf(mt, __shfl_xor(mt, 2));
            mt = fmaxf(mt, __shfl_xor(mt, 4));
            mt = fmaxf(mt, __shfl_xor(mt, 8));
            float mn = fmaxf(m[r], mt);
            float corr = __expf(m[r] - mn);
            m[r] = mn;
            float ps = 0.f;
#pragma unroll
            for (int n = 0; n < 4; ++n) {
                float p = __expf(accS[n][r] - mn);
                accS[n][r] = p;
                ps += p;
            }
            ps += __shfl_xor(ps, 1);
            ps += __shfl_xor(ps, 2);
            ps += __shfl_xor(ps, 4);
            ps += __shfl_xor(ps, 8);
            l[r] = l[r] * corr + ps;
#pragma unroll
            for (int n2 = 0; n2 < 4; ++n2) accO[n2][r] *= corr;
        }

#pragma unroll
        for (int r = 0; r < 4; ++r)
#pragma unroll
            for (int n = 0; n < 4; ++n) {
                u16 hh, ll;
                split2(accS[n][r], hh, ll);
                sPh[w][lg * 4 + r][n * 16 + lr] = hh;
                sPl[w][lg * 4 + r][n * 16 + lr] = ll;
            }
        __syncthreads();

#pragma unroll
        for (int n2 = 0; n2 < 4; ++n2)
#pragma unroll
            for (int c = 0; c < 2; ++c) {
                s16x8 ph = *reinterpret_cast<const s16x8*>(&sPh[w][lr][c * 32 + lg * 8]);
                s16x8 pl = *reinterpret_cast<const s16x8*>(&sPl[w][lr][c * 32 + lg * 8]);
                s16x8 vh = *reinterpret_cast<const s16x8*>(&sVh[n2 * 16 + lr][c * 32 + lg * 8]);
                s16x8 vl = *reinterpret_cast<const s16x8*>(&sVl[n2 * 16 + lr][c * 32 + lg * 8]);
                accO[n2] = __builtin_amdgcn_mfma_f32_16x16x32_bf16(ph, vh, accO[n2], 0, 0, 0);
                accO[n2] = __builtin_amdgcn_mfma_f32_16x16x32_bf16(ph, vl, accO[n2], 0, 0, 0);
                accO[n2] = __builtin_amdgcn_mfma_f32_16x16x32_bf16(pl, vh, accO[n2], 0, 0, 0);
            }
    }

#pragma unroll
    for (int r = 0; r < 4; ++r) {
        float inv = 1.f / l[r];
        float* op = o_out + (size_t)(b * C_L + qt * 64 + w * 16 + lg * 4 + r) * C_NHID + h * 64;
#pragma unroll
        for (int n2 = 0; n2 < 4; ++n2)
            op[n2 * 16 + lr] = accO[n2][r] * inv;
    }
}

// ---------------- batched 64x64 SGEMM (per-z strides, no epilogue) ----------
__global__ __launch_bounds__(256) void sgemm64b_kernel(
    const void* __restrict__ A, int aIn, size_t aOff, size_t zA,
    const void* __restrict__ Wt, int wIn, size_t wOff, size_t zW,
    const int* __restrict__ flag,
    float* __restrict__ C, size_t zC, int M, int K, int Nc)
{
    const bool f32in = (*flag) != 0;
    const bool aF32 = aIn ? f32in : true;
    const bool wF32 = wIn ? f32in : true;
    const size_t za = aOff + (size_t)blockIdx.z * zA;
    const size_t zw = wOff + (size_t)blockIdx.z * zW;
    float* Cz = C + (size_t)blockIdx.z * zC;

    __shared__ float sA[16][68];
    __shared__ float sB[16][68];
    const int tid = threadIdx.x;
    const int tx = tid & 15, ty = tid >> 4;
    const int bm = blockIdx.y << 6, bn = blockIdx.x << 6;
    float acc[4][4] = {};
    const int la_r = tid >> 2;
    const int la_c = (tid & 3) << 2;
    const int lb_r = tid >> 4;
    const int lb_c = (tid & 15) << 2;

    for (int k0 = 0; k0 < K; k0 += 16) {
        float a0, a1, a2, a3, b0, b1, b2, b3;
        ld4(A, za + (size_t)(bm + la_r) * K + k0 + la_c, aF32, a0, a1, a2, a3);
        ld4(Wt, zw + (size_t)(k0 + lb_r) * Nc + bn + lb_c, wF32, b0, b1, b2, b3);
        sA[la_c + 0][la_r] = a0; sA[la_c + 1][la_r] = a1;
        sA[la_c + 2][la_r] = a2; sA[la_c + 3][la_r] = a3;
        sB[lb_r][lb_c + 0] = b0; sB[lb_r][lb_c + 1] = b1;
        sB[lb_r][lb_c + 2] = b2; sB[lb_r][lb_c + 3] = b3;
        __syncthreads();
#pragma unroll
        for (int kk = 0; kk < 16; ++kk) {
            float av[4], bv[4];
#pragma unroll
            for (int i = 0; i < 4; ++i) av[i] = sA[kk][(ty << 2) + i];
#pragma unroll
            for (int j = 0; j < 4; ++j) bv[j] = sB[kk][(tx << 2) + j];
#pragma unroll
            for (int i = 0; i < 4; ++i)
#pragma unroll
                for (int j = 0; j < 4; ++j)
                    acc[i][j] += av[i] * bv[j];
        }
        __syncthreads();
    }
#pragma unroll
    for (int i = 0; i < 4; ++i)
#pragma unroll
        for (int j = 0; j < 4; ++j)
            Cz[(size_t)(bm + (ty << 2) + i) * Nc + bn + (tx << 2) + j] = acc[i][j];
}

// GcT hi/lo pair: GcT_g[(slot*64+c)][k] = split(Gtmp[i][k][c])
__global__ __launch_bounds__(256) void gcatT2_kernel(
    const float* __restrict__ Gtmp,
    u16* __restrict__ G0h, u16* __restrict__ G0l,
    u16* __restrict__ G1h, u16* __restrict__ G1l)
{
    int idx = blockIdx.x * 256 + threadIdx.x;
    int i = idx >> 15, rem = idx & 32767;
    int k = rem >> 6, c = rem & 63;
    int g = (i >> 1) & 1;
    int slot = (i & 1) + ((i >> 2) << 1);
    u16 h, l;
    split2(Gtmp[idx], h, l);
    size_t o = (size_t)(slot * 64 + c) * 512 + k;
    if (g) { G1h[o] = h; G1l[o] = l; }
    else   { G0h[o] = h; G0l[o] = l; }
}

// ---------------- GNN kernels ----------------
__global__ __launch_bounds__(256) void xfcopy_kernel(
    const float* __restrict__ h, float* __restrict__ xf)
{
    int idx = blockIdx.x * 256 + threadIdx.x;
    int n = idx >> 9, c = idx & 511;
    int b = n / C_S;
    int s = n - b * C_S;
    xf[idx] = h[(((size_t)(b * C_L + 1 + s)) << 9) + c];
}

__global__ __launch_bounds__(256) void degi_kernel(
    const int* __restrict__ gs, const int* __restrict__ gd,
    const int* __restrict__ as_, const int* __restrict__ ad,
    int* __restrict__ ideg0, int* __restrict__ ideg1,
    float* __restrict__ outd0, float* __restrict__ outd1)
{
    int e = blockIdx.x * 256 + threadIdx.x;
    if (e >= C_E) return;
    atomicAdd(&ideg0[gd[e]], 1);
    atomicAdd(&ideg1[ad[e]], 1);
    atomicAdd(&outd0[gs[e]], 1.f);
    atomicAdd(&outd1[as_[e]], 1.f);
}

__global__ __launch_bounds__(1024) void scan_kernel(
    const int* __restrict__ i0, const int* __restrict__ i1,
    int* __restrict__ r0, int* __restrict__ r1)
{
    __shared__ int part[1024];
    const int t = threadIdx.x;
    const int* d = blockIdx.x ? i1 : i0;
    int* rs = blockIdx.x ? r1 : r0;
    int v[8]; int s = 0;
#pragma unroll
    for (int i = 0; i < 8; ++i) {
        int idx = t * 8 + i;
        v[i] = (idx < C_N) ? d[idx] : 0;
        s += v[i];
    }
    part[t] = s;
    __syncthreads();
    for (int off = 1; off < 1024; off <<= 1) {
        int x = (t >= off) ? part[t - off] : 0;
        __syncthreads();
        part[t] += x;
        __syncthreads();
    }
    int run = part[t] - s;   // exclusive
#pragma unroll
    for (int i = 0; i < 8; ++i) {
        int idx = t * 8 + i;
        if (idx <= C_N) rs[idx] = run;
        run += v[i];
    }
}

__global__ __launch_bounds__(256) void fill_kernel(
    const int* __restrict__ gs, const int* __restrict__ gd,
    const int* __restrict__ as_, const int* __restrict__ ad,
    const int* __restrict__ rs0, const int* __restrict__ rs1,
    int* __restrict__ cur0, int* __restrict__ cur1,
    int* __restrict__ csr0, int* __restrict__ csr1)
{
    int e = blockIdx.x * 256 + threadIdx.x;
    if (e >= C_E) return;
    int d0 = gd[e];
    int p = atomicAdd(&cur0[d0], 1);
    csr0[rs0[d0] + p] = gs[e];
    int d1 = ad[e];
    int q = atomicAdd(&cur1[d1], 1);
    csr1[rs1[d1] + q] = as_[e];
}

__global__ __launch_bounds__(256) void gatherA_kernel(
    const float* __restrict__ X, const int* __restrict__ csr,
    const int* __restrict__ rs, float* __restrict__ Y)
{
    const int n = blockIdx.x;
    const int tid = threadIdx.x;
    const int s0 = rs[n], s1 = rs[n + 1];
    const size_t o = (size_t)n * 512;
    float a0 = X[o + tid], a1 = X[o + tid + 256];
    for (int e = s0; e < s1; ++e) {
        const size_t so = (size_t)csr[e] * 512;
        a0 += X[so + tid];
        a1 += X[so + tid + 256];
    }
    const float r = 1.f / (float)(s1 - s0 + 1);
    Y[o + tid] = a0 * r;
    Y[o + tid + 256] = a1 * r;
}

__global__ __launch_bounds__(256) void gatherF_kernel(
    const float* __restrict__ F, const int* __restrict__ csr,
    const int* __restrict__ rs, float* __restrict__ xcagg,
    int c0, int c1, int c2, int c3)
{
    const int n = blockIdx.x;
    const int c = threadIdx.x;             // 0..255
    const int s0 = rs[n], s1 = rs[n + 1];
    float acc = 0.f;
    for (int e = s0; e < s1; ++e)
        acc += F[(size_t)csr[e] * 256 + c];
    const int s = c >> 6, cc = c & 63;
    const int cmap = (s == 0) ? c0 : (s == 1) ? c1 : (s == 2) ? c2 : c3;
    xcagg[(size_t)n * 512 + cmap + cc] = acc;
}

__global__ __launch_bounds__(256) void fxc_kernel(
    float* __restrict__ xcagg, const int* __restrict__ rs0,
    const int* __restrict__ rs1, const void* __restrict__ g3b,
    const int* __restrict__ flag)
{
    const bool f = (*flag) != 0;
    unsigned idx = blockIdx.x * 256 + threadIdx.x;
    int n = idx >> 7;
    int c = (idx & 127) << 2;
    int hh = c >> 6;
    int g = (hh >> 1) & 1;
    const int* rs = g ? rs1 : rs0;
    float ind = (float)(rs[n + 1] - rs[n]);
    float r = rsqrtf(fmaxf(ind, 1.f));
    size_t o = (size_t)n * 512 + c;
    float4 v = *reinterpret_cast<float4*>(xcagg + o);
    v.x = v.x * r + ldin(g3b, c, f);     v.y = v.y * r + ldin(g3b, c + 1, f);
    v.z = v.z * r + ldin(g3b, c + 2, f); v.w = v.w * r + ldin(g3b, c + 3, f);
    *reinterpret_cast<float4*>(xcagg + o) = v;
}

// dc[i][c] = sum_k s1b[i][k]*T8[i][k*64+c] + s2b[i][k]*g3w[i][k*64+c]
__global__ __launch_bounds__(512) void dvec_kernel(
    const void* __restrict__ s1b, const void* __restrict__ s2b,
    const void* __restrict__ g3w, const float* __restrict__ T8,
    const int* __restrict__ flag, float* __restrict__ dc0, float* __restrict__ dc1)
{
    const bool f = (*flag) != 0;
    const int i = blockIdx.x;
    const int c = threadIdx.x & 63;
    const int kg = threadIdx.x >> 6;       // 0..7
    const float* T = T8 + (size_t)i * 32768;
    float acc = 0.f;
    const int kbeg = kg * 64, kend = kbeg + 64;
    for (int k = kbeg; k < kend; ++k)
        acc += ldin(s1b, (size_t)i * 512 + k, f) * T[k * 64 + c]
             + ldin(s2b, (size_t)i * 512 + k, f) * ldin(g3w, (size_t)i * 32768 + (size_t)k * 64 + c, f);
    __shared__ float red[8][64];
    red[kg][c] = acc;
    __syncthreads();
    if (kg == 0) {
        float v = red[0][c] + red[1][c] + red[2][c] + red[3][c]
                + red[4][c] + red[5][c] + red[6][c] + red[7][c];
        int g = (i >> 1) & 1;
        int slot = (i & 1) + ((i >> 2) << 1);
        (g ? dc1 : dc0)[slot * 64 + c] = v;
    }
}

// ---------------- LayerNorm ----------------
__global__ __launch_bounds__(256) void ln_kernel(
    const float* __restrict__ in, const float* __restrict__ res,
    const void* __restrict__ gw, const void* __restrict__ bw,
    const int* __restrict__ flag, float* __restrict__ out)
{
    const bool f = (*flag) != 0;
    int row = blockIdx.x;
    int tid = threadIdx.x;
    const float* x = in + (size_t)row * 512;
    float v0 = x[tid], v1 = x[tid + 256];
    __shared__ float red[4];
    float s = v0 + v1;
#pragma unroll
    for (int off = 32; off > 0; off >>= 1) s += __shfl_down(s, off);
    if ((tid & 63) == 0) red[tid >> 6] = s;
    __syncthreads();
    float mu = (red[0] + red[1] + red[2] + red[3]) * (1.f / 512.f);
    __syncthreads();
    float d0 = v0 - mu, d1 = v1 - mu;
    s = d0 * d0 + d1 * d1;
#pragma unroll
    for (int off = 32; off > 0; off >>= 1) s += __shfl_down(s, off);
    if ((tid & 63) == 0) red[tid >> 6] = s;
    __syncthreads();
    float var = (red[0] + red[1] + red[2] + red[3]) * (1.f / 512.f);
    float rstd = rsqrtf(var + 1e-5f);
    size_t o = (size_t)row * 512;
    float r0 = d0 * rstd * ldin(gw, tid, f)       + ldin(bw, tid, f);
    float r1 = d1 * rstd * ldin(gw, tid + 256, f) + ldin(bw, tid + 256, f);
    if (res) { r0 += res[o + tid]; r1 += res[o + tid + 256]; }
    out[o + tid] = r0;
    out[o + tid + 256] = r1;
}

// ---------------- output conversion ----------------
__global__ __launch_bounds__(256) void out_zbar_kernel(
    const float* __restrict__ z, void* __restrict__ out, const int* __restrict__ flag)
{
    const bool f = (*flag) != 0;
    int idx = blockIdx.x * 256 + threadIdx.x;
    if (f) ((float*)out)[idx] = z[idx];
    else   ((bf16*)out)[idx]  = __float2bfloat16(z[idx]);
}

__global__ __launch_bounds__(256) void out_zg_kernel(
    const float* __restrict__ h, void* __restrict__ out, const int* __restrict__ flag)
{
    const bool f = (*flag) != 0;
    int idx = blockIdx.x * 256 + threadIdx.x;
    int b = idx >> 9, c = idx & 511;
    float v = h[(size_t)b * C_L * 512 + c];
    size_t o = (size_t)C_N * 512 + idx;
    if (f) ((float*)out)[o] = v;
    else   ((bf16*)out)[o]  = __float2bfloat16(v);
}

// ---------------- host-side wrappers ----------------
static inline void msgemm(hipStream_t st,
    const float* A, const u16* Bh, const u16* Bl,
    const void* biasB, size_t bOff, const float* biasF,
    const float* res, float resScale, const float* rowDeg, int relu,
    const int* flag, float* C, int M, int K, int Nc, int ldc)
{
    dim3 g(Nc / 64, (M + 127) / 128);
    msgemm_kernel<<<g, dim3(256), 0, st>>>(A, Bh, Bl, biasB, bOff, biasF,
                                           res, resScale, rowDeg, relu, flag,
                                           C, M, K, Nc, ldc);
}

static inline void msgemm2(hipStream_t st,
    const float* A, const u16* Bh, const u16* Bl,
    const void* biasB, size_t bOff, int relu,
    const int* flag, float* C, int M, int K, int Nc, int ldc)
{
    dim3 g(Nc / 128, (M + 127) / 128);
    msgemm2_kernel<<<g, dim3(256), 0, st>>>(A, Bh, Bl, biasB, bOff, relu, flag,
                                            C, M, K, Nc, ldc);
}

static inline void wtrans2(hipStream_t st, const void* Wsrc, size_t srcOff,
                           const int* flag, u16* Bh, u16* Bl, int K, int N)
{
    wtrans2_kernel<<<dim3(N / 32, K / 32), dim3(256), 0, st>>>(
        Wsrc, srcOff, flag, Bh, Bl, K, N);
}

extern "C" void kernel_launch(void* const* d_in, const int* in_sizes, int n_in,
                              void* d_out, int out_size, void* d_ws, size_t ws_size,
                              hipStream_t stream)
{
    const void* emb   = d_in[0];
    const void* pos   = d_in[1];
    const void* qkv_w = d_in[2];
    const void* qkv_b = d_in[3];
    const void* aow   = d_in[4];
    const void* aob   = d_in[5];
    const void* ff1w  = d_in[6];
    const void* ff1b  = d_in[7];
    const void* ff2w  = d_in[8];
    const void* ff2b  = d_in[9];
    const void* s1w   = d_in[10];
    const void* s1b   = d_in[11];
    const void* s2w   = d_in[12];
    const void* s2b   = d_in[13];
    const void* g3w   = d_in[14];
    const void* g3b   = d_in[15];
    const void* gf1w  = d_in[16];
    const void* gf1b  = d_in[17];
    const void* gf2w  = d_in[18];
    const void* gf2b  = d_in[19];
    const void* lng   = d_in[20];
    const void* lnb   = d_in[21];
    const int* idxs   = (const int*)d_in[22];
    const int* gts    = (const int*)d_in[24];
    const int* gtd    = (const int*)d_in[25];
    const int* ats    = (const int*)d_in[26];
    const int* atd    = (const int*)d_in[27];

    float* W = (float*)d_ws;
    float* h    = W + OFF_H;
    float* qkvb = W + OFF_QKV;
    float* ob   = W + OFF_O;
    float* xb   = W + OFF_X;
    float* midb = W + OFF_MID;
    int* flag   = (int*)(W + OFF_FLAG);

    detect_kernel<<<dim3(1), dim3(1), 0, stream>>>((const unsigned*)lng, flag);

    // ===== transformer (GEMMs + attention on matrix cores, bf16x2 split) =====
    embed_kernel<<<dim3(C_MTOK), dim3(256), 0, stream>>>(emb, pos, idxs, flag, h);

    // stream-ordered dead-scratch for split weights (zero extra workspace):
    u16* qkvT = (u16*)ob;                       // dead until attn writes ob
    u16* aoT  = (u16*)midb;                     // dead until FF1 writes midb
    u16* ffT  = (u16*)qkvb;                     // dead after attn consumed qkvb

    for (int l = 0; l < 4; ++l) {
        wtrans2(stream, qkv_w, (size_t)l * 512 * 1536, flag,
                qkvT, qkvT + 786432, 512, 1536);
        msgemm2(stream, h, qkvT, qkvT + 786432, qkv_b, (size_t)l * 1536,
                0, flag, qkvb, C_MTOK, 512, 1536, 1536);
        mattn_kernel<<<dim3(1024), dim3(256), 0, stream>>>(qkvb, ob);
        wtrans2(stream, aow, (size_t)l * 512 * 512, flag,
                aoT, aoT + 262144, 512, 512);
        msgemm(stream, ob, aoT, aoT + 262144, aob, (size_t)l * 512, nullptr,
               h, 2.f, nullptr, 0, flag, xb, C_MTOK, 512, 512, 512);
        wtrans2(stream, ff1w, (size_t)l * 512 * 2048, flag,
                ffT, ffT + 1048576, 512, 2048);
        msgemm2(stream, xb, ffT, ffT + 1048576, ff1b, (size_t)l * 2048,
                1, flag, midb, C_MTOK, 512, 2048, 2048);
        wtrans2(stream, ff2w, (size_t)l * 2048 * 512, flag,
                ffT + 2097152, ffT + 3145728, 2048, 512);
        msgemm(stream, midb, ffT + 2097152, ffT + 3145728, ff2b, (size_t)l * 512, nullptr,
               xb, 1.f, nullptr, 0, flag, h, C_MTOK, 2048, 512, 512);
    }

    // ===== GNN =====
    float* xf    = ob;
    float* Z0    = qkvb;
    float* Z1    = qkvb + 4194304;
    float* Yb    = qkvb + 8388608;
    float* Gtmp  = Yb;                       // precompute staging, dead before gathers
    float* Fb    = xb;
    float* zbar  = xb;
    float* xcagg = midb;
    float* xgnn  = midb + 4194304;
    float* fmid  = midb + 8388608;
    float* fout  = midb + 12582912;
    float* T8    = W + OFF_T8;
    float* dc0   = W + OFF_DCAT0;
    float* dc1   = W + OFF_DCAT1;
    float* outd0 = W + OFF_DEG;
    float* outd1 = outd0 + 8192;
    u16* GcT0h = (u16*)(W + OFF_GCAT0);
    u16* GcT0l = GcT0h + 131072;
    u16* GcT1h = (u16*)(W + OFF_GCAT1);
    u16* GcT1l = GcT1h + 131072;
    u16* gfT   = (u16*)Yb;

    int* ibase = (int*)fmid;
    int* rs0   = ibase;              // 8208
    int* rs1   = ibase + 8208;       // 8208
    int* ideg0 = ibase + 16416;      // 8192
    int* ideg1 = ibase + 24608;      // 8192
    int* cur0  = ibase + 32800;      // 8192
    int* cur1  = ibase + 40992;      // 8192
    int* csr0  = ibase + 49184;      // 131072
    int* csr1  = ibase + 180256;     // 131072

    xfcopy_kernel<<<dim3(C_N * 512 / 256), dim3(256), 0, stream>>>(h, xf);

    // ---- CSR build ----
    (void)hipMemsetAsync(ideg0, 0, 2 * 8192 * sizeof(int), stream);
    (void)hipMemsetAsync(cur0, 0, 2 * 8192 * sizeof(int), stream);
    (void)hipMemsetAsync(outd0, 0, 2 * 8192 * sizeof(float), stream);
    degi_kernel<<<dim3(C_E / 256), dim3(256), 0, stream>>>(
        gts, gtd, ats, atd, ideg0, ideg1, outd0, outd1);
    scan_kernel<<<dim3(2), dim3(1024), 0, stream>>>(ideg0, ideg1, rs0, rs1);
    fill_kernel<<<dim3(C_E / 256), dim3(256), 0, stream>>>(
        gts, gtd, ats, atd, rs0, rs1, cur0, cur1, csr0, csr1);

    // ---- per-head weight precompute ----
    sgemm64b_kernel<<<dim3(1, 8, 8), dim3(256), 0, stream>>>(
        s2w, 1, 0, 262144, g3w, 1, 0, 32768, flag, T8, 32768, 512, 512, 64);
    sgemm64b_kernel<<<dim3(1, 8, 8), dim3(256), 0, stream>>>(
        s1w, 1, 0, 262144, T8, 0, 0, 32768, flag, Gtmp, 32768, 512, 512, 64);
    gcatT2_kernel<<<dim3(1024), dim3(256), 0, stream>>>(Gtmp, GcT0h, GcT0l, GcT1h, GcT1l);
    dvec_kernel<<<dim3(8), dim3(512), 0, stream>>>(s1b, s2b, g3w, T8, flag, dc0, dc1);

    // ---- A^2 x per graph (gather, fused normalize) ----
    gatherA_kernel<<<dim3(C_N), dim3(256), 0, stream>>>(xf, csr0, rs0, Yb);
    gatherA_kernel<<<dim3(C_N), dim3(256), 0, stream>>>(Yb, csr0, rs0, Z0);
    gatherA_kernel<<<dim3(C_N), dim3(256), 0, stream>>>(xf, csr1, rs1, Yb);
    gatherA_kernel<<<dim3(C_N), dim3(256), 0, stream>>>(Yb, csr1, rs1, Z1);

    // ---- F_g = (Z_g @ Gcat_g + d_g) * outdnorm_g ; gather into xcagg slots ----
    msgemm(stream, Z0, GcT0h, GcT0l, nullptr, 0, dc0, nullptr, 0.f, outd0, 0, flag,
           Fb, C_N, 512, 256, 256);
    gatherF_kernel<<<dim3(C_N), dim3(256), 0, stream>>>(
        Fb, csr0, rs0, xcagg, 0, 64, 256, 320);
    msgemm(stream, Z1, GcT1h, GcT1l, nullptr, 0, dc1, nullptr, 0.f, outd1, 0, flag,
           Fb, C_N, 512, 256, 256);
    gatherF_kernel<<<dim3(C_N), dim3(256), 0, stream>>>(
        Fb, csr1, rs1, xcagg, 128, 192, 384, 448);
    fxc_kernel<<<dim3(C_N * 128 / 256), dim3(256), 0, stream>>>(
        xcagg, rs0, rs1, g3b, flag);

    // ---- GNN FF + LNs (gf weights -> Yb scratch, dead after gathers) ----
    ln_kernel<<<dim3(C_N), dim3(256), 0, stream>>>(xcagg, xf, lng, lnb, flag, xgnn);
    wtrans2(stream, gf1w, 0, flag, gfT, gfT + 262144, 512, 512);
    msgemm(stream, xgnn, gfT, gfT + 262144, gf1b, 0, nullptr,
           nullptr, 0.f, nullptr, 1, flag, fmid, C_N, 512, 512, 512);
    wtrans2(stream, gf2w, 0, flag, gfT + 524288, gfT + 786432, 512, 512);
    msgemm(stream, fmid, gfT + 524288, gfT + 786432, gf2b, 0, nullptr,
           nullptr, 0.f, nullptr, 0, flag, fout, C_N, 512, 512, 512);
    ln_kernel<<<dim3(C_N), dim3(256), 0, stream>>>(fout, xgnn, lng, lnb, flag, zbar);

    out_zbar_kernel<<<dim3(C_N * 512 / 256), dim3(256), 0, stream>>>(zbar, d_out, flag);
    out_zg_kernel<<<dim3(32), dim3(256), 0, stream>>>(h, d_out, flag);
}

// Round 8
// 2044.240 us; speedup vs baseline: 1.1164x; 1.1164x over previous
//
#include <hip/hip_runtime.h>
#include <hip/hip_bf16.h>

typedef __hip_bfloat16 bf16;
typedef unsigned short u16;
typedef __attribute__((ext_vector_type(8))) short s16x8;   // 8 bf16 (4 VGPRs)
typedef __attribute__((ext_vector_type(4))) float f32x4;   // MFMA accumulator

// ---------------- dtype-agnostic input loads ----------------
__device__ __forceinline__ float bfb(unsigned short b) {
    union { unsigned u; float f; } v; v.u = ((unsigned)b) << 16; return v.f;
}
__device__ __forceinline__ float ldin(const void* p, size_t i, bool f32) {
    return f32 ? ((const float*)p)[i] : bfb(((const unsigned short*)p)[i]);
}
__device__ __forceinline__ void ld4(const void* p, size_t i, bool f32,
                                    float& x, float& y, float& z, float& w) {
    if (f32) {
        float4 v = *reinterpret_cast<const float4*>((const float*)p + i);
        x = v.x; y = v.y; z = v.z; w = v.w;
    } else {
        ushort4 u = *reinterpret_cast<const ushort4*>((const unsigned short*)p + i);
        x = bfb(u.x); y = bfb(u.y); z = bfb(u.z); w = bfb(u.w);
    }
}
__device__ __forceinline__ u16 f2b(float x) {
    bf16 h = __float2bfloat16(x);
    return *reinterpret_cast<u16*>(&h);
}
// bf16x2 split: x = hi + lo, hi = truncate-to-bf16 (exact), lo = RN-bf16(x - hi)
__device__ __forceinline__ void split2(float x, u16& h, u16& l) {
    unsigned u = __float_as_uint(x);
    h = (u16)(u >> 16);
    float rem = x - __uint_as_float(u & 0xFFFF0000u);
    l = f2b(rem);
}
// XCD-aware block swizzle (T1)
__device__ __forceinline__ int xcd_swz(int F, int nwg) {
    return ((nwg & 7) == 0) ? ((F & 7) * (nwg >> 3) + (F >> 3)) : F;
}

// ---------------- problem constants ----------------
constexpr int C_B = 16, C_S = 511, C_L = 512, C_NHID = 512;
constexpr int C_N = C_B * C_S;       // 8176
constexpr int C_MTOK = C_B * C_L;    // 8192
constexpr int C_E = 131072;
constexpr int C_QKVD = 1536;

// ---------------- workspace layout (f32 element offsets) ----------------
enum : size_t {
    OFF_H     = 0,
    OFF_QKV   = 4194304,
    OFF_O     = 16777216,
    OFF_X     = 20971520,
    OFF_MID   = 25165824,
    OFF_PRE   = 41943040,
    OFF_T8    = OFF_PRE,
    OFF_GCAT0 = OFF_PRE + 262144,
    OFF_GCAT1 = OFF_GCAT0 + 131072,
    OFF_DCAT0 = OFF_GCAT1 + 131072,
    OFF_DCAT1 = OFF_DCAT0 + 256,
    OFF_DEG   = OFF_DCAT1 + 256,
    OFF_FLAG  = OFF_DEG + 32768
};

// ---------------- dtype detection ----------------
__global__ void detect_kernel(const unsigned* __restrict__ g, int* __restrict__ flag) {
    *flag = (g[0] == 0x3F800000u) ? 1 : 0;
}

// ---------------- embedding ----------------
__global__ __launch_bounds__(256) void embed_kernel(
    const void* __restrict__ emb, const void* __restrict__ pos,
    const int* __restrict__ idxs, const int* __restrict__ flag,
    float* __restrict__ h)
{
    const bool f = (*flag) != 0;
    int token = blockIdx.x;
    int tid = threadIdx.x;
    int b = token >> 9, t = token & 511;
    int id = (t == 0) ? 0 : idxs[b * C_S + t - 1];
    size_t eo = (size_t)id * C_NHID, po = (size_t)t * C_NHID, ho = (size_t)token * C_NHID;
    h[ho + tid]       = ldin(emb, eo + tid, f)       + ldin(pos, po + tid, f);
    h[ho + tid + 256] = ldin(emb, eo + tid + 256, f) + ldin(pos, po + tid + 256, f);
}

// ---------------- weight transpose + bf16x2 split (dtype via flag) ----------
__global__ __launch_bounds__(256) void wtrans2_kernel(
    const void* __restrict__ Wsrc, size_t srcOff, const int* __restrict__ flag,
    u16* __restrict__ Bh, u16* __restrict__ Bl, int K, int N)
{
    const bool f = (*flag) != 0;
    __shared__ float s[32][33];
    int nb = blockIdx.x << 5, kb = blockIdx.y << 5;
    int c = threadIdx.x & 31, r0 = (threadIdx.x >> 5) << 2;
#pragma unroll
    for (int i = 0; i < 4; ++i)
        s[r0 + i][c] = ldin(Wsrc, srcOff + (size_t)(kb + r0 + i) * N + nb + c, f);
    __syncthreads();
#pragma unroll
    for (int i = 0; i < 4; ++i) {
        u16 h, l;
        split2(s[c][r0 + i], h, l);
        size_t o = (size_t)(nb + r0 + i) * K + kb + c;
        Bh[o] = h; Bl[o] = l;
    }
}

// ---------------- MFMA bf16x2-SPLIT GEMM, 64x64 tile ------------------------
// Small-N GEMMs (FF2/AO/GF/F). 4 waves own 32x32 quadrants (2x2). Grid is
// 2-4x larger than the 128x64 tiling -> 4 blocks/CU -> independent wave
// streams hide the per-step serial chain (m114 overlap).
__global__ __launch_bounds__(256, 4) void msgemm64_kernel(
    const float* __restrict__ A,
    const u16* __restrict__ Bh, const u16* __restrict__ Bl,
    const void* __restrict__ biasB, size_t bOff,
    const float* __restrict__ biasF,
    const float* __restrict__ res, float resScale,
    const float* __restrict__ rowDeg, int relu,
    const int* __restrict__ flag,
    float* __restrict__ C, int M, int K, int Nc, int ldc)
{
    const bool f32in = (*flag) != 0;
    __shared__ __align__(16) u16 sAh[64][40];
    __shared__ __align__(16) u16 sAl[64][40];
    __shared__ __align__(16) u16 sBh[64][40];
    __shared__ __align__(16) u16 sBl[64][40];
    const int tid = threadIdx.x;
    const int nwg = gridDim.x * gridDim.y;
    const int swz = xcd_swz(blockIdx.y * gridDim.x + blockIdx.x, nwg);
    const int bm = (swz / gridDim.x) << 6, bn = (swz % gridDim.x) << 6;
    const int lane = tid & 63, lr = lane & 15, lg = lane >> 4;
    const int wave = tid >> 6, wm = wave >> 1, wn = wave & 1;

    f32x4 acc[2][2];
#pragma unroll
    for (int m = 0; m < 2; ++m)
#pragma unroll
        for (int n = 0; n < 2; ++n) {
            f32x4 z = {0.f, 0.f, 0.f, 0.f};
            acc[m][n] = z;
        }

    const int sr = tid >> 2, sk = (tid & 3) << 3;   // row 0..63, k chunk of 8
    const int am = bm + sr;
    const bool aok = am < M;
    const float* ap = A + (size_t)am * K + sk;
    const u16* bph = Bh + (size_t)(bn + sr) * K + sk;
    const u16* bpl = Bl + (size_t)(bn + sr) * K + sk;

    for (int k0 = 0; k0 < K; k0 += 32) {
        u16 tah[8], tal[8];
        if (aok) {
            float4 v0 = *reinterpret_cast<const float4*>(ap + k0);
            float4 v1 = *reinterpret_cast<const float4*>(ap + k0 + 4);
            split2(v0.x, tah[0], tal[0]); split2(v0.y, tah[1], tal[1]);
            split2(v0.z, tah[2], tal[2]); split2(v0.w, tah[3], tal[3]);
            split2(v1.x, tah[4], tal[4]); split2(v1.y, tah[5], tal[5]);
            split2(v1.z, tah[6], tal[6]); split2(v1.w, tah[7], tal[7]);
        } else {
#pragma unroll
            for (int i = 0; i < 8; ++i) { tah[i] = 0; tal[i] = 0; }
        }
        s16x8 bh0 = *reinterpret_cast<const s16x8*>(bph + k0);
        s16x8 bl0 = *reinterpret_cast<const s16x8*>(bpl + k0);

        *reinterpret_cast<s16x8*>(&sAh[sr][sk]) = *reinterpret_cast<s16x8*>(&tah[0]);
        *reinterpret_cast<s16x8*>(&sAl[sr][sk]) = *reinterpret_cast<s16x8*>(&tal[0]);
        *reinterpret_cast<s16x8*>(&sBh[sr][sk]) = bh0;
        *reinterpret_cast<s16x8*>(&sBl[sr][sk]) = bl0;
        __syncthreads();

        s16x8 fah[2], fal[2], fbh[2], fbl[2];
#pragma unroll
        for (int m = 0; m < 2; ++m) {
            fah[m] = *reinterpret_cast<const s16x8*>(&sAh[wm * 32 + m * 16 + lr][lg * 8]);
            fal[m] = *reinterpret_cast<const s16x8*>(&sAl[wm * 32 + m * 16 + lr][lg * 8]);
        }
#pragma unroll
        for (int n = 0; n < 2; ++n) {
            fbh[n] = *reinterpret_cast<const s16x8*>(&sBh[wn * 32 + n * 16 + lr][lg * 8]);
            fbl[n] = *reinterpret_cast<const s16x8*>(&sBl[wn * 32 + n * 16 + lr][lg * 8]);
        }
#pragma unroll
        for (int m = 0; m < 2; ++m)
#pragma unroll
            for (int n = 0; n < 2; ++n) {
                acc[m][n] = __builtin_amdgcn_mfma_f32_16x16x32_bf16(fah[m], fbh[n], acc[m][n], 0, 0, 0);
                acc[m][n] = __builtin_amdgcn_mfma_f32_16x16x32_bf16(fah[m], fbl[n], acc[m][n], 0, 0, 0);
                acc[m][n] = __builtin_amdgcn_mfma_f32_16x16x32_bf16(fal[m], fbh[n], acc[m][n], 0, 0, 0);
            }
        __syncthreads();
    }

    // D layout (m89-verified): col = lane&15, row = (lane>>4)*4 + reg
#pragma unroll
    for (int m = 0; m < 2; ++m) {
#pragma unroll
        for (int r = 0; r < 4; ++r) {
            int row = bm + wm * 32 + m * 16 + lg * 4 + r;
            if (row >= M) continue;
            float rs = rowDeg ? rsqrtf(fmaxf(rowDeg[row], 1.f)) : 1.f;
#pragma unroll
            for (int n = 0; n < 2; ++n) {
                int col = bn + wn * 32 + n * 16 + lr;
                float v = acc[m][n][r];
                if (biasB) v += ldin(biasB, bOff + col, f32in);
                if (biasF) v += biasF[col];
                v *= rs;
                if (res) v += resScale * res[(size_t)row * Nc + col];
                if (relu) v = fmaxf(v, 0.f);
                C[(size_t)row * ldc + col] = v;
            }
        }
    }
}

// ---------------- MFMA bf16x2-SPLIT GEMM, 128x128 tile (big-N GEMMs) ---------
__global__ __launch_bounds__(256, 2) void msgemm2_kernel(
    const float* __restrict__ A,
    const u16* __restrict__ Bh, const u16* __restrict__ Bl,
    const void* __restrict__ biasB, size_t bOff,
    const int relu, const int* __restrict__ flag,
    float* __restrict__ C, int M, int K, int Nc, int ldc)
{
    const bool f32in = (*flag) != 0;
    __shared__ __align__(16) u16 sAh[128][40];
    __shared__ __align__(16) u16 sAl[128][40];
    __shared__ __align__(16) u16 sBh[128][40];
    __shared__ __align__(16) u16 sBl[128][40];
    const int tid = threadIdx.x;
    const int nwg = gridDim.x * gridDim.y;
    const int swz = xcd_swz(blockIdx.y * gridDim.x + blockIdx.x, nwg);
    const int bm = (swz / gridDim.x) << 7, bn = (swz % gridDim.x) << 7;
    const int lane = tid & 63, lr = lane & 15, lg = lane >> 4;
    const int wave = tid >> 6, wm = wave >> 1, wn = wave & 1;

    f32x4 acc[4][4];
#pragma unroll
    for (int m = 0; m < 4; ++m)
#pragma unroll
        for (int n = 0; n < 4; ++n) {
            f32x4 z = {0.f, 0.f, 0.f, 0.f};
            acc[m][n] = z;
        }

    const int sr = tid >> 1, sk = (tid & 1) << 4;
    const int am = bm + sr;
    const bool aok = am < M;
    const float* ap = A + (size_t)am * K + sk;
    const u16* bph = Bh + (size_t)(bn + sr) * K + sk;
    const u16* bpl = Bl + (size_t)(bn + sr) * K + sk;

    for (int k0 = 0; k0 < K; k0 += 32) {
        u16 tah[16], tal[16];
        if (aok) {
#pragma unroll
            for (int i = 0; i < 16; i += 4) {
                float4 v = *reinterpret_cast<const float4*>(ap + k0 + i);
                split2(v.x, tah[i],     tal[i]);
                split2(v.y, tah[i + 1], tal[i + 1]);
                split2(v.z, tah[i + 2], tal[i + 2]);
                split2(v.w, tah[i + 3], tal[i + 3]);
            }
        } else {
#pragma unroll
            for (int i = 0; i < 16; ++i) { tah[i] = 0; tal[i] = 0; }
        }
        s16x8 bh0 = *reinterpret_cast<const s16x8*>(bph + k0);
        s16x8 bh1 = *reinterpret_cast<const s16x8*>(bph + k0 + 8);
        s16x8 bl0 = *reinterpret_cast<const s16x8*>(bpl + k0);
        s16x8 bl1 = *reinterpret_cast<const s16x8*>(bpl + k0 + 8);

        *reinterpret_cast<s16x8*>(&sAh[sr][sk])     = *reinterpret_cast<s16x8*>(&tah[0]);
        *reinterpret_cast<s16x8*>(&sAh[sr][sk + 8]) = *reinterpret_cast<s16x8*>(&tah[8]);
        *reinterpret_cast<s16x8*>(&sAl[sr][sk])     = *reinterpret_cast<s16x8*>(&tal[0]);
        *reinterpret_cast<s16x8*>(&sAl[sr][sk + 8]) = *reinterpret_cast<s16x8*>(&tal[8]);
        *reinterpret_cast<s16x8*>(&sBh[sr][sk])     = bh0;
        *reinterpret_cast<s16x8*>(&sBh[sr][sk + 8]) = bh1;
        *reinterpret_cast<s16x8*>(&sBl[sr][sk])     = bl0;
        *reinterpret_cast<s16x8*>(&sBl[sr][sk + 8]) = bl1;
        __syncthreads();

        s16x8 fah[4], fal[4], fbh[4], fbl[4];
#pragma unroll
        for (int m = 0; m < 4; ++m) {
            fah[m] = *reinterpret_cast<const s16x8*>(&sAh[wm * 64 + m * 16 + lr][lg * 8]);
            fal[m] = *reinterpret_cast<const s16x8*>(&sAl[wm * 64 + m * 16 + lr][lg * 8]);
        }
#pragma unroll
        for (int n = 0; n < 4; ++n) {
            fbh[n] = *reinterpret_cast<const s16x8*>(&sBh[wn * 64 + n * 16 + lr][lg * 8]);
            fbl[n] = *reinterpret_cast<const s16x8*>(&sBl[wn * 64 + n * 16 + lr][lg * 8]);
        }
#pragma unroll
        for (int m = 0; m < 4; ++m)
#pragma unroll
            for (int n = 0; n < 4; ++n) {
                acc[m][n] = __builtin_amdgcn_mfma_f32_16x16x32_bf16(fah[m], fbh[n], acc[m][n], 0, 0, 0);
                acc[m][n] = __builtin_amdgcn_mfma_f32_16x16x32_bf16(fah[m], fbl[n], acc[m][n], 0, 0, 0);
                acc[m][n] = __builtin_amdgcn_mfma_f32_16x16x32_bf16(fal[m], fbh[n], acc[m][n], 0, 0, 0);
            }
        __syncthreads();
    }

#pragma unroll
    for (int m = 0; m < 4; ++m) {
#pragma unroll
        for (int r = 0; r < 4; ++r) {
            int row = bm + wm * 64 + m * 16 + lg * 4 + r;
            if (row >= M) continue;
#pragma unroll
            for (int n = 0; n < 4; ++n) {
                int col = bn + wn * 64 + n * 16 + lr;
                float v = acc[m][n][r];
                if (biasB) v += ldin(biasB, bOff + col, f32in);
                if (relu) v = fmaxf(v, 0.f);
                C[(size_t)row * ldc + col] = v;
            }
        }
    }
}

// ---------------- MFMA bf16x2-split flash attention ------------------------
__global__ __launch_bounds__(256) void mattn_kernel(
    const float* __restrict__ qkv, float* __restrict__ o_out)
{
    __shared__ __align__(16) u16 sKh[64][72], sKl[64][72];   // [kp][d]
    __shared__ __align__(16) u16 sVh[64][72], sVl[64][72];   // [dv][kp] (V^T)
    __shared__ __align__(16) u16 sPh[4][16][72], sPl[4][16][72];
    const int blk = xcd_swz(blockIdx.x, gridDim.x);   // same-(b,h) blocks -> same XCD
    const int b = blk >> 6, h = (blk >> 3) & 7, qt = blk & 7;
    const int tid = threadIdx.x;
    const int lane = tid & 63, lr = lane & 15, lg = lane >> 4;
    const int w = tid >> 6;

    s16x8 qh[2], ql[2];
    {
        const float* qp = qkv + (size_t)(b * C_L + qt * 64 + w * 16 + lr) * C_QKVD + h * 192;
#pragma unroll
        for (int c = 0; c < 2; ++c) {
            int d0 = c * 32 + lg * 8;
            u16 th[8], tl[8];
#pragma unroll
            for (int i = 0; i < 8; i += 4) {
                float4 v = *reinterpret_cast<const float4*>(qp + d0 + i);
                split2(v.x * 0.125f, th[i],     tl[i]);
                split2(v.y * 0.125f, th[i + 1], tl[i + 1]);
                split2(v.z * 0.125f, th[i + 2], tl[i + 2]);
                split2(v.w * 0.125f, th[i + 3], tl[i + 3]);
            }
            qh[c] = *reinterpret_cast<s16x8*>(th);
            ql[c] = *reinterpret_cast<s16x8*>(tl);
        }
    }

    f32x4 accO[4];
#pragma unroll
    for (int n = 0; n < 4; ++n) { f32x4 z = {0.f, 0.f, 0.f, 0.f}; accO[n] = z; }
    float m[4] = {-3.0e38f, -3.0e38f, -3.0e38f, -3.0e38f};
    float l[4] = {0.f, 0.f, 0.f, 0.f};

    const float* kvb = qkv + (size_t)b * C_L * C_QKVD + h * 192;
    const int kp = tid >> 2;
    const int d0 = (tid & 3) << 4;

    for (int jt = 0; jt < 8; ++jt) {
        __syncthreads();
        {
            const float* kr = kvb + (size_t)(jt * 64 + kp) * C_QKVD + 64 + d0;
            const float* vr = kr + 64;
#pragma unroll
            for (int i = 0; i < 16; i += 4) {
                float4 kv = *reinterpret_cast<const float4*>(kr + i);
                float4 vv = *reinterpret_cast<const float4*>(vr + i);
                u16 th[4], tl[4];
                split2(kv.x, th[0], tl[0]); split2(kv.y, th[1], tl[1]);
                split2(kv.z, th[2], tl[2]); split2(kv.w, th[3], tl[3]);
                *reinterpret_cast<ushort4*>(&sKh[kp][d0 + i]) = *reinterpret_cast<ushort4*>(th);
                *reinterpret_cast<ushort4*>(&sKl[kp][d0 + i]) = *reinterpret_cast<ushort4*>(tl);
                u16 hh, ll;
                split2(vv.x, hh, ll); sVh[d0 + i][kp]     = hh; sVl[d0 + i][kp]     = ll;
                split2(vv.y, hh, ll); sVh[d0 + i + 1][kp] = hh; sVl[d0 + i + 1][kp] = ll;
                split2(vv.z, hh, ll); sVh[d0 + i + 2][kp] = hh; sVl[d0 + i + 2][kp] = ll;
                split2(vv.w, hh, ll); sVh[d0 + i + 3][kp] = hh; sVl[d0 + i + 3][kp] = ll;
            }
        }
        __syncthreads();

        f32x4 accS[4];
#pragma unroll
        for (int n = 0; n < 4; ++n) { f32x4 z = {0.f, 0.f, 0.f, 0.f}; accS[n] = z; }
#pragma unroll
        for (int n = 0; n < 4; ++n)
#pragma unroll
            for (int c = 0; c < 2; ++c) {
                s16x8 kh = *reinterpret_cast<const s16x8*>(&sKh[n * 16 + lr][c * 32 + lg * 8]);
                s16x8 kl = *reinterpret_cast<const s16x8*>(&sKl[n * 16 + lr][c * 32 + lg * 8]);
                accS[n] = __builtin_amdgcn_mfma_f32_16x16x32_bf16(qh[c], kh, accS[n], 0, 0, 0);
                accS[n] = __builtin_amdgcn_mfma_f32_16x16x32_bf16(qh[c], kl, accS[n], 0, 0, 0);
                accS[n] = __builtin_amdgcn_mfma_f32_16x16x32_bf16(ql[c], kh, accS[n], 0, 0, 0);
            }

#pragma unroll
        for (int r = 0; r < 4; ++r) {
            float mt = fmaxf(fmaxf(accS[0][r], accS[1][r]), fmaxf(accS[2][r], accS[3][r]));
            mt = fmaxf(mt, __shfl_xor(mt, 1));
            mt = fmaxf(mt, __shfl_xor(mt, 2));
            mt = fmaxf(mt, __shfl_xor(mt, 4));
            mt = fmaxf(mt, __shfl_xor(mt, 8));
            float mn = fmaxf(m[r], mt);
            float corr = __expf(m[r] - mn);
            m[r] = mn;
            float ps = 0.f;
#pragma unroll
            for (int n = 0; n < 4; ++n) {
                float p = __expf(accS[n][r] - mn);
                accS[n][r] = p;
                ps += p;
            }
            ps += __shfl_xor(ps, 1);
            ps += __shfl_xor(ps, 2);
            ps += __shfl_xor(ps, 4);
            ps += __shfl_xor(ps, 8);
            l[r] = l[r] * corr + ps;
#pragma unroll
            for (int n2 = 0; n2 < 4; ++n2) accO[n2][r] *= corr;
        }

#pragma unroll
        for (int r = 0; r < 4; ++r)
#pragma unroll
            for (int n = 0; n < 4; ++n) {
                u16 hh, ll;
                split2(accS[n][r], hh, ll);
                sPh[w][lg * 4 + r][n * 16 + lr] = hh;
                sPl[w][lg * 4 + r][n * 16 + lr] = ll;
            }
        __syncthreads();

#pragma unroll
        for (int n2 = 0; n2 < 4; ++n2)
#pragma unroll
            for (int c = 0; c < 2; ++c) {
                s16x8 ph = *reinterpret_cast<const s16x8*>(&sPh[w][lr][c * 32 + lg * 8]);
                s16x8 pl = *reinterpret_cast<const s16x8*>(&sPl[w][lr][c * 32 + lg * 8]);
                s16x8 vh = *reinterpret_cast<const s16x8*>(&sVh[n2 * 16 + lr][c * 32 + lg * 8]);
                s16x8 vl = *reinterpret_cast<const s16x8*>(&sVl[n2 * 16 + lr][c * 32 + lg * 8]);
                accO[n2] = __builtin_amdgcn_mfma_f32_16x16x32_bf16(ph, vh, accO[n2], 0, 0, 0);
                accO[n2] = __builtin_amdgcn_mfma_f32_16x16x32_bf16(ph, vl, accO[n2], 0, 0, 0);
                accO[n2] = __builtin_amdgcn_mfma_f32_16x16x32_bf16(pl, vh, accO[n2], 0, 0, 0);
            }
    }

#pragma unroll
    for (int r = 0; r < 4; ++r) {
        float inv = 1.f / l[r];
        float* op = o_out + (size_t)(b * C_L + qt * 64 + w * 16 + lg * 4 + r) * C_NHID + h * 64;
#pragma unroll
        for (int n2 = 0; n2 < 4; ++n2)
            op[n2 * 16 + lr] = accO[n2][r] * inv;
    }
}

// ---------------- batched 64x64 SGEMM (per-z strides, no epilogue) ----------
__global__ __launch_bounds__(256) void sgemm64b_kernel(
    const void* __restrict__ A, int aIn, size_t aOff, size_t zA,
    const void* __restrict__ Wt, int wIn, size_t wOff, size_t zW,
    const int* __restrict__ flag,
    float* __restrict__ C, size_t zC, int M, int K, int Nc)
{
    const bool f32in = (*flag) != 0;
    const bool aF32 = aIn ? f32in : true;
    const bool wF32 = wIn ? f32in : true;
    const size_t za = aOff + (size_t)blockIdx.z * zA;
    const size_t zw = wOff + (size_t)blockIdx.z * zW;
    float* Cz = C + (size_t)blockIdx.z * zC;

    __shared__ float sA[16][68];
    __shared__ float sB[16][68];
    const int tid = threadIdx.x;
    const int tx = tid & 15, ty = tid >> 4;
    const int bm = blockIdx.y << 6, bn = blockIdx.x << 6;
    float acc[4][4] = {};
    const int la_r = tid >> 2;
    const int la_c = (tid & 3) << 2;
    const int lb_r = tid >> 4;
    const int lb_c = (tid & 15) << 2;

    for (int k0 = 0; k0 < K; k0 += 16) {
        float a0, a1, a2, a3, b0, b1, b2, b3;
        ld4(A, za + (size_t)(bm + la_r) * K + k0 + la_c, aF32, a0, a1, a2, a3);
        ld4(Wt, zw + (size_t)(k0 + lb_r) * Nc + bn + lb_c, wF32, b0, b1, b2, b3);
        sA[la_c + 0][la_r] = a0; sA[la_c + 1][la_r] = a1;
        sA[la_c + 2][la_r] = a2; sA[la_c + 3][la_r] = a3;
        sB[lb_r][lb_c + 0] = b0; sB[lb_r][lb_c + 1] = b1;
        sB[lb_r][lb_c + 2] = b2; sB[lb_r][lb_c + 3] = b3;
        __syncthreads();
#pragma unroll
        for (int kk = 0; kk < 16; ++kk) {
            float av[4], bv[4];
#pragma unroll
            for (int i = 0; i < 4; ++i) av[i] = sA[kk][(ty << 2) + i];
#pragma unroll
            for (int j = 0; j < 4; ++j) bv[j] = sB[kk][(tx << 2) + j];
#pragma unroll
            for (int i = 0; i < 4; ++i)
#pragma unroll
                for (int j = 0; j < 4; ++j)
                    acc[i][j] += av[i] * bv[j];
        }
        __syncthreads();
    }
#pragma unroll
    for (int i = 0; i < 4; ++i)
#pragma unroll
        for (int j = 0; j < 4; ++j)
            Cz[(size_t)(bm + (ty << 2) + i) * Nc + bn + (tx << 2) + j] = acc[i][j];
}

// GcT hi/lo pair: GcT_g[(slot*64+c)][k] = split(Gtmp[i][k][c])
__global__ __launch_bounds__(256) void gcatT2_kernel(
    const float* __restrict__ Gtmp,
    u16* __restrict__ G0h, u16* __restrict__ G0l,
    u16* __restrict__ G1h, u16* __restrict__ G1l)
{
    int idx = blockIdx.x * 256 + threadIdx.x;
    int i = idx >> 15, rem = idx & 32767;
    int k = rem >> 6, c = rem & 63;
    int g = (i >> 1) & 1;
    int slot = (i & 1) + ((i >> 2) << 1);
    u16 h, l;
    split2(Gtmp[idx], h, l);
    size_t o = (size_t)(slot * 64 + c) * 512 + k;
    if (g) { G1h[o] = h; G1l[o] = l; }
    else   { G0h[o] = h; G0l[o] = l; }
}

// ---------------- GNN kernels ----------------
__global__ __launch_bounds__(256) void xfcopy_kernel(
    const float* __restrict__ h, float* __restrict__ xf)
{
    int idx = blockIdx.x * 256 + threadIdx.x;
    int n = idx >> 9, c = idx & 511;
    int b = n / C_S;
    int s = n - b * C_S;
    xf[idx] = h[(((size_t)(b * C_L + 1 + s)) << 9) + c];
}

__global__ __launch_bounds__(256) void degi_kernel(
    const int* __restrict__ gs, const int* __restrict__ gd,
    const int* __restrict__ as_, const int* __restrict__ ad,
    int* __restrict__ ideg0, int* __restrict__ ideg1,
    float* __restrict__ outd0, float* __restrict__ outd1)
{
    int e = blockIdx.x * 256 + threadIdx.x;
    if (e >= C_E) return;
    atomicAdd(&ideg0[gd[e]], 1);
    atomicAdd(&ideg1[ad[e]], 1);
    atomicAdd(&outd0[gs[e]], 1.f);
    atomicAdd(&outd1[as_[e]], 1.f);
}

__global__ __launch_bounds__(1024) void scan_kernel(
    const int* __restrict__ i0, const int* __restrict__ i1,
    int* __restrict__ r0, int* __restrict__ r1)
{
    __shared__ int part[1024];
    const int t = threadIdx.x;
    const int* d = blockIdx.x ? i1 : i0;
    int* rs = blockIdx.x ? r1 : r0;
    int v[8]; int s = 0;
#pragma unroll
    for (int i = 0; i < 8; ++i) {
        int idx = t * 8 + i;
        v[i] = (idx < C_N) ? d[idx] : 0;
        s += v[i];
    }
    part[t] = s;
    __syncthreads();
    for (int off = 1; off < 1024; off <<= 1) {
        int x = (t >= off) ? part[t - off] : 0;
        __syncthreads();
        part[t] += x;
        __syncthreads();
    }
    int run = part[t] - s;   // exclusive
#pragma unroll
    for (int i = 0; i < 8; ++i) {
        int idx = t * 8 + i;
        if (idx <= C_N) rs[idx] = run;
        run += v[i];
    }
}

__global__ __launch_bounds__(256) void fill_kernel(
    const int* __restrict__ gs, const int* __restrict__ gd,
    const int* __restrict__ as_, const int* __restrict__ ad,
    const int* __restrict__ rs0, const int* __restrict__ rs1,
    int* __restrict__ cur0, int* __restrict__ cur1,
    int* __restrict__ csr0, int* __restrict__ csr1)
{
    int e = blockIdx.x * 256 + threadIdx.x;
    if (e >= C_E) return;
    int d0 = gd[e];
    int p = atomicAdd(&cur0[d0], 1);
    csr0[rs0[d0] + p] = gs[e];
    int d1 = ad[e];
    int q = atomicAdd(&cur1[d1], 1);
    csr1[rs1[d1] + q] = as_[e];
}

__global__ __launch_bounds__(256) void gatherA_kernel(
    const float* __restrict__ X, const int* __restrict__ csr,
    const int* __restrict__ rs, float* __restrict__ Y)
{
    const int n = blockIdx.x;
    const int tid = threadIdx.x;
    const int s0 = rs[n], s1 = rs[n + 1];
    const size_t o = (size_t)n * 512;
    float a0 = X[o + tid], a1 = X[o + tid + 256];
    for (int e = s0; e < s1; ++e) {
        const size_t so = (size_t)csr[e] * 512;
        a0 += X[so + tid];
        a1 += X[so + tid + 256];
    }
    const float r = 1.f / (float)(s1 - s0 + 1);
    Y[o + tid] = a0 * r;
    Y[o + tid + 256] = a1 * r;
}

__global__ __launch_bounds__(256) void gatherF_kernel(
    const float* __restrict__ F, const int* __restrict__ csr,
    const int* __restrict__ rs, float* __restrict__ xcagg,
    int c0, int c1, int c2, int c3)
{
    const int n = blockIdx.x;
    const int c = threadIdx.x;             // 0..255
    const int s0 = rs[n], s1 = rs[n + 1];
    float acc = 0.f;
    for (int e = s0; e < s1; ++e)
        acc += F[(size_t)csr[e] * 256 + c];
    const int s = c >> 6, cc = c & 63;
    const int cmap = (s == 0) ? c0 : (s == 1) ? c1 : (s == 2) ? c2 : c3;
    xcagg[(size_t)n * 512 + cmap + cc] = acc;
}

__global__ __launch_bounds__(256) void fxc_kernel(
    float* __restrict__ xcagg, const int* __restrict__ rs0,
    const int* __restrict__ rs1, const void* __restrict__ g3b,
    const int* __restrict__ flag)
{
    const bool f = (*flag) != 0;
    unsigned idx = blockIdx.x * 256 + threadIdx.x;
    int n = idx >> 7;
    int c = (idx & 127) << 2;
    int hh = c >> 6;
    int g = (hh >> 1) & 1;
    const int* rs = g ? rs1 : rs0;
    float ind = (float)(rs[n + 1] - rs[n]);
    float r = rsqrtf(fmaxf(ind, 1.f));
    size_t o = (size_t)n * 512 + c;
    float4 v = *reinterpret_cast<float4*>(xcagg + o);
    v.x = v.x * r + ldin(g3b, c, f);     v.y = v.y * r + ldin(g3b, c + 1, f);
    v.z = v.z * r + ldin(g3b, c + 2, f); v.w = v.w * r + ldin(g3b, c + 3, f);
    *reinterpret_cast<float4*>(xcagg + o) = v;
}

// dc[i][c] = sum_k s1b[i][k]*T8[i][k*64+c] + s2b[i][k]*g3w[i][k*64+c]
__global__ __launch_bounds__(512) void dvec_kernel(
    const void* __restrict__ s1b, const void* __restrict__ s2b,
    const void* __restrict__ g3w, const float* __restrict__ T8,
    const int* __restrict__ flag, float* __restrict__ dc0, float* __restrict__ dc1)
{
    const bool f = (*flag) != 0;
    const int i = blockIdx.x;
    const int c = threadIdx.x & 63;
    const int kg = threadIdx.x >> 6;       // 0..7
    const float* T = T8 + (size_t)i * 32768;
    float acc = 0.f;
    const int kbeg = kg * 64, kend = kbeg + 64;
    for (int k = kbeg; k < kend; ++k)
        acc += ldin(s1b, (size_t)i * 512 + k, f) * T[k * 64 + c]
             + ldin(s2b, (size_t)i * 512 + k, f) * ldin(g3w, (size_t)i * 32768 + (size_t)k * 64 + c, f);
    __shared__ float red[8][64];
    red[kg][c] = acc;
    __syncthreads();
    if (kg == 0) {
        float v = red[0][c] + red[1][c] + red[2][c] + red[3][c]
                + red[4][c] + red[5][c] + red[6][c] + red[7][c];
        int g = (i >> 1) & 1;
        int slot = (i & 1) + ((i >> 2) << 1);
        (g ? dc1 : dc0)[slot * 64 + c] = v;
    }
}

// ---------------- LayerNorm ----------------
__global__ __launch_bounds__(256) void ln_kernel(
    const float* __restrict__ in, const float* __restrict__ res,
    const void* __restrict__ gw, const void* __restrict__ bw,
    const int* __restrict__ flag, float* __restrict__ out)
{
    const bool f = (*flag) != 0;
    int row = blockIdx.x;
    int tid = threadIdx.x;
    const float* x = in + (size_t)row * 512;
    float v0 = x[tid], v1 = x[tid + 256];
    __shared__ float red[4];
    float s = v0 + v1;
#pragma unroll
    for (int off = 32; off > 0; off >>= 1) s += __shfl_down(s, off);
    if ((tid & 63) == 0) red[tid >> 6] = s;
    __syncthreads();
    float mu = (red[0] + red[1] + red[2] + red[3]) * (1.f / 512.f);
    __syncthreads();
    float d0 = v0 - mu, d1 = v1 - mu;
    s = d0 * d0 + d1 * d1;
#pragma unroll
    for (int off = 32; off > 0; off >>= 1) s += __shfl_down(s, off);
    if ((tid & 63) == 0) red[tid >> 6] = s;
    __syncthreads();
    float var = (red[0] + red[1] + red[2] + red[3]) * (1.f / 512.f);
    float rstd = rsqrtf(var + 1e-5f);
    size_t o = (size_t)row * 512;
    float r0 = d0 * rstd * ldin(gw, tid, f)       + ldin(bw, tid, f);
    float r1 = d1 * rstd * ldin(gw, tid + 256, f) + ldin(bw, tid + 256, f);
    if (res) { r0 += res[o + tid]; r1 += res[o + tid + 256]; }
    out[o + tid] = r0;
    out[o + tid + 256] = r1;
}

// ---------------- output conversion ----------------
__global__ __launch_bounds__(256) void out_zbar_kernel(
    const float* __restrict__ z, void* __restrict__ out, const int* __restrict__ flag)
{
    const bool f = (*flag) != 0;
    int idx = blockIdx.x * 256 + threadIdx.x;
    if (f) ((float*)out)[idx] = z[idx];
    else   ((bf16*)out)[idx]  = __float2bfloat16(z[idx]);
}

__global__ __launch_bounds__(256) void out_zg_kernel(
    const float* __restrict__ h, void* __restrict__ out, const int* __restrict__ flag)
{
    const bool f = (*flag) != 0;
    int idx = blockIdx.x * 256 + threadIdx.x;
    int b = idx >> 9, c = idx & 511;
    float v = h[(size_t)b * C_L * 512 + c];
    size_t o = (size_t)C_N * 512 + idx;
    if (f) ((float*)out)[o] = v;
    else   ((bf16*)out)[o]  = __float2bfloat16(v);
}

// ---------------- host-side wrappers ----------------
static inline void msgemm(hipStream_t st,
    const float* A, const u16* Bh, const u16* Bl,
    const void* biasB, size_t bOff, const float* biasF,
    const float* res, float resScale, const float* rowDeg, int relu,
    const int* flag, float* C, int M, int K, int Nc, int ldc)
{
    dim3 g(Nc / 64, (M + 63) / 64);
    msgemm64_kernel<<<g, dim3(256), 0, st>>>(A, Bh, Bl, biasB, bOff, biasF,
                                             res, resScale, rowDeg, relu, flag,
                                             C, M, K, Nc, ldc);
}

static inline void msgemm2(hipStream_t st,
    const float* A, const u16* Bh, const u16* Bl,
    const void* biasB, size_t bOff, int relu,
    const int* flag, float* C, int M, int K, int Nc, int ldc)
{
    dim3 g(Nc / 128, (M + 127) / 128);
    msgemm2_kernel<<<g, dim3(256), 0, st>>>(A, Bh, Bl, biasB, bOff, relu, flag,
                                            C, M, K, Nc, ldc);
}

static inline void wtrans2(hipStream_t st, const void* Wsrc, size_t srcOff,
                           const int* flag, u16* Bh, u16* Bl, int K, int N)
{
    wtrans2_kernel<<<dim3(N / 32, K / 32), dim3(256), 0, st>>>(
        Wsrc, srcOff, flag, Bh, Bl, K, N);
}

extern "C" void kernel_launch(void* const* d_in, const int* in_sizes, int n_in,
                              void* d_out, int out_size, void* d_ws, size_t ws_size,
                              hipStream_t stream)
{
    const void* emb   = d_in[0];
    const void* pos   = d_in[1];
    const void* qkv_w = d_in[2];
    const void* qkv_b = d_in[3];
    const void* aow   = d_in[4];
    const void* aob   = d_in[5];
    const void* ff1w  = d_in[6];
    const void* ff1b  = d_in[7];
    const void* ff2w  = d_in[8];
    const void* ff2b  = d_in[9];
    const void* s1w   = d_in[10];
    const void* s1b   = d_in[11];
    const void* s2w   = d_in[12];
    const void* s2b   = d_in[13];
    const void* g3w   = d_in[14];
    const void* g3b   = d_in[15];
    const void* gf1w  = d_in[16];
    const void* gf1b  = d_in[17];
    const void* gf2w  = d_in[18];
    const void* gf2b  = d_in[19];
    const void* lng   = d_in[20];
    const void* lnb   = d_in[21];
    const int* idxs   = (const int*)d_in[22];
    const int* gts    = (const int*)d_in[24];
    const int* gtd    = (const int*)d_in[25];
    const int* ats    = (const int*)d_in[26];
    const int* atd    = (const int*)d_in[27];

    float* W = (float*)d_ws;
    float* h    = W + OFF_H;
    float* qkvb = W + OFF_QKV;
    float* ob   = W + OFF_O;
    float* xb   = W + OFF_X;
    float* midb = W + OFF_MID;
    int* flag   = (int*)(W + OFF_FLAG);

    detect_kernel<<<dim3(1), dim3(1), 0, stream>>>((const unsigned*)lng, flag);

    // ===== transformer (GEMMs + attention on matrix cores, bf16x2 split) =====
    embed_kernel<<<dim3(C_MTOK), dim3(256), 0, stream>>>(emb, pos, idxs, flag, h);

    // stream-ordered dead-scratch for split weights (zero extra workspace):
    u16* qkvT = (u16*)ob;                       // dead until attn writes ob
    u16* aoT  = (u16*)midb;                     // dead until FF1 writes midb
    u16* ffT  = (u16*)qkvb;                     // dead after attn consumed qkvb

    for (int l = 0; l < 4; ++l) {
        wtrans2(stream, qkv_w, (size_t)l * 512 * 1536, flag,
                qkvT, qkvT + 786432, 512, 1536);
        msgemm2(stream, h, qkvT, qkvT + 786432, qkv_b, (size_t)l * 1536,
                0, flag, qkvb, C_MTOK, 512, 1536, 1536);
        mattn_kernel<<<dim3(1024), dim3(256), 0, stream>>>(qkvb, ob);
        wtrans2(stream, aow, (size_t)l * 512 * 512, flag,
                aoT, aoT + 262144, 512, 512);
        msgemm(stream, ob, aoT, aoT + 262144, aob, (size_t)l * 512, nullptr,
               h, 2.f, nullptr, 0, flag, xb, C_MTOK, 512, 512, 512);
        wtrans2(stream, ff1w, (size_t)l * 512 * 2048, flag,
                ffT, ffT + 1048576, 512, 2048);
        msgemm2(stream, xb, ffT, ffT + 1048576, ff1b, (size_t)l * 2048,
                1, flag, midb, C_MTOK, 512, 2048, 2048);
        wtrans2(stream, ff2w, (size_t)l * 2048 * 512, flag,
                ffT + 2097152, ffT + 3145728, 2048, 512);
        msgemm(stream, midb, ffT + 2097152, ffT + 3145728, ff2b, (size_t)l * 512, nullptr,
               xb, 1.f, nullptr, 0, flag, h, C_MTOK, 2048, 512, 512);
    }

    // ===== GNN =====
    float* xf    = ob;
    float* Z0    = qkvb;
    float* Z1    = qkvb + 4194304;
    float* Yb    = qkvb + 8388608;
    float* Gtmp  = Yb;                       // precompute staging, dead before gathers
    float* Fb    = xb;
    float* zbar  = xb;
    float* xcagg = midb;
    float* xgnn  = midb + 4194304;
    float* fmid  = midb + 8388608;
    float* fout  = midb + 12582912;
    float* T8    = W + OFF_T8;
    float* dc0   = W + OFF_DCAT0;
    float* dc1   = W + OFF_DCAT1;
    float* outd0 = W + OFF_DEG;
    float* outd1 = outd0 + 8192;
    u16* GcT0h = (u16*)(W + OFF_GCAT0);
    u16* GcT0l = GcT0h + 131072;
    u16* GcT1h = (u16*)(W + OFF_GCAT1);
    u16* GcT1l = GcT1h + 131072;
    u16* gfT   = (u16*)Yb;

    int* ibase = (int*)fmid;
    int* rs0   = ibase;              // 8208
    int* rs1   = ibase + 8208;       // 8208
    int* ideg0 = ibase + 16416;      // 8192
    int* ideg1 = ibase + 24608;      // 8192
    int* cur0  = ibase + 32800;      // 8192
    int* cur1  = ibase + 40992;      // 8192
    int* csr0  = ibase + 49184;      // 131072
    int* csr1  = ibase + 180256;     // 131072

    xfcopy_kernel<<<dim3(C_N * 512 / 256), dim3(256), 0, stream>>>(h, xf);

    // ---- CSR build ----
    (void)hipMemsetAsync(ideg0, 0, 2 * 8192 * sizeof(int), stream);
    (void)hipMemsetAsync(cur0, 0, 2 * 8192 * sizeof(int), stream);
    (void)hipMemsetAsync(outd0, 0, 2 * 8192 * sizeof(float), stream);
    degi_kernel<<<dim3(C_E / 256), dim3(256), 0, stream>>>(
        gts, gtd, ats, atd, ideg0, ideg1, outd0, outd1);
    scan_kernel<<<dim3(2), dim3(1024), 0, stream>>>(ideg0, ideg1, rs0, rs1);
    fill_kernel<<<dim3(C_E / 256), dim3(256), 0, stream>>>(
        gts, gtd, ats, atd, rs0, rs1, cur0, cur1, csr0, csr1);

    // ---- per-head weight precompute ----
    sgemm64b_kernel<<<dim3(1, 8, 8), dim3(256), 0, stream>>>(
        s2w, 1, 0, 262144, g3w, 1, 0, 32768, flag, T8, 32768, 512, 512, 64);
    sgemm64b_kernel<<<dim3(1, 8, 8), dim3(256), 0, stream>>>(
        s1w, 1, 0, 262144, T8, 0, 0, 32768, flag, Gtmp, 32768, 512, 512, 64);
    gcatT2_kernel<<<dim3(1024), dim3(256), 0, stream>>>(Gtmp, GcT0h, GcT0l, GcT1h, GcT1l);
    dvec_kernel<<<dim3(8), dim3(512), 0, stream>>>(s1b, s2b, g3w, T8, flag, dc0, dc1);

    // ---- A^2 x per graph (gather, fused normalize) ----
    gatherA_kernel<<<dim3(C_N), dim3(256), 0, stream>>>(xf, csr0, rs0, Yb);
    gatherA_kernel<<<dim3(C_N), dim3(256), 0, stream>>>(Yb, csr0, rs0, Z0);
    gatherA_kernel<<<dim3(C_N), dim3(256), 0, stream>>>(xf, csr1, rs1, Yb);
    gatherA_kernel<<<dim3(C_N), dim3(256), 0, stream>>>(Yb, csr1, rs1, Z1);

    // ---- F_g = (Z_g @ Gcat_g + d_g) * outdnorm_g ; gather into xcagg slots ----
    msgemm(stream, Z0, GcT0h, GcT0l, nullptr, 0, dc0, nullptr, 0.f, outd0, 0, flag,
           Fb, C_N, 512, 256, 256);
    gatherF_kernel<<<dim3(C_N), dim3(256), 0, stream>>>(
        Fb, csr0, rs0, xcagg, 0, 64, 256, 320);
    msgemm(stream, Z1, GcT1h, GcT1l, nullptr, 0, dc1, nullptr, 0.f, outd1, 0, flag,
           Fb, C_N, 512, 256, 256);
    gatherF_kernel<<<dim3(C_N), dim3(256), 0, stream>>>(
        Fb, csr1, rs1, xcagg, 128, 192, 384, 448);
    fxc_kernel<<<dim3(C_N * 128 / 256), dim3(256), 0, stream>>>(
        xcagg, rs0, rs1, g3b, flag);

    // ---- GNN FF + LNs (gf weights -> Yb scratch, dead after gathers) ----
    ln_kernel<<<dim3(C_N), dim3(256), 0, stream>>>(xcagg, xf, lng, lnb, flag, xgnn);
    wtrans2(stream, gf1w, 0, flag, gfT, gfT + 262144, 512, 512);
    msgemm(stream, xgnn, gfT, gfT + 262144, gf1b, 0, nullptr,
           nullptr, 0.f, nullptr, 1, flag, fmid, C_N, 512, 512, 512);
    wtrans2(stream, gf2w, 0, flag, gfT + 524288, gfT + 786432, 512, 512);
    msgemm(stream, fmid, gfT + 524288, gfT + 786432, gf2b, 0, nullptr,
           nullptr, 0.f, nullptr, 0, flag, fout, C_N, 512, 512, 512);
    ln_kernel<<<dim3(C_N), dim3(256), 0, stream>>>(fout, xgnn, lng, lnb, flag, zbar);

    out_zbar_kernel<<<dim3(C_N * 512 / 256), dim3(256), 0, stream>>>(zbar, d_out, flag);
    out_zg_kernel<<<dim3(32), dim3(256), 0, stream>>>(h, d_out, flag);
}